// Round 11
// baseline (996.274 us; speedup 1.0000x reference)
//
#include <hip/hip_runtime.h>
#include <hip/hip_bf16.h>

// StencilNet round 10: k_mid as 1-block/CU double-buffered tile pipeline.
// R5-R9 lesson: launch_bounds(512,4) caps regs at 128 incl. 64 AGPR acc ->
// every staging/epilogue addition spilled. Now (512,2): 256-reg budget,
// two LDS act buffers, each block pipelines 4 consecutive tiles
// (issue loads -> compute cur -> ds_write next -> barrier -> stores after).

#define HW   256
#define MASK 255
#define CH   64
#define TX   32
#define TY   16

typedef short bf16x8 __attribute__((ext_vector_type(8)));
typedef float f32x4  __attribute__((ext_vector_type(4)));

__device__ __forceinline__ float bf2f(unsigned short u) {
    return __uint_as_float(((unsigned int)u) << 16);
}
__device__ __forceinline__ unsigned short f2bf(float f) {
    unsigned int x = __float_as_uint(f);
    return (unsigned short)((x + 0x7fffu + ((x >> 16) & 1u)) >> 16);  // RNE
}

// ---- pack mid-layer weights into 16x16x32 B-frag layout (bf16) -------------
__global__ __launch_bounds__(512) void k_pack(
    const float* __restrict__ w1, const float* __restrict__ w2,
    const float* __restrict__ w3, const float* __restrict__ w4,
    unsigned short* __restrict__ dst)
{
    int g = blockIdx.x * 512 + threadIdx.x;
    if (g >= 4 * 4608) return;
    int L = g / 4608, r = g - L * 4608;
    const float* w = (L == 0) ? w1 : (L == 1) ? w2 : (L == 2) ? w3 : w4;
    int q = r >> 8, n = (r >> 6) & 3, l = r & 63;
    int tap = q >> 1, s = q & 1;
    int ci0 = s * 32 + ((l >> 4) << 3);
    int co  = n * 16 + (l & 15);
    unsigned short o8[8];
#pragma unroll
    for (int j = 0; j < 8; j++)
        o8[j] = f2bf(w[(tap * 64 + ci0 + j) * 64 + co]);
    *reinterpret_cast<uint4*>(dst + (size_t)g * 8) = *reinterpret_cast<uint4*>(o8);
}

// ---------------- Layer 0: [C,vx,vy] (3ch f32) -> 64ch bf16, ReLU -------------
__global__ __launch_bounds__(512) void k_layer0(
    const float* __restrict__ Cin, const float* __restrict__ vx,
    const float* __restrict__ vy, const float* __restrict__ w0,
    const float* __restrict__ b0, unsigned short* __restrict__ out)
{
    int t  = threadIdx.x;
    int lx = t & 31, ly = t >> 5;
    int x  = blockIdx.x * TX + lx;
    int y  = blockIdx.y * TY + ly;
    int bb = blockIdx.z;
    int pbase = bb * HW * HW;

    float a[27];
#pragma unroll
    for (int ky = 0; ky < 3; ky++) {
        int yy = (y + ky - 1) & MASK;
#pragma unroll
        for (int kx = 0; kx < 3; kx++) {
            int xx  = (x + kx - 1) & MASK;
            int idx = pbase + yy * HW + xx;
            a[(ky * 3 + kx) * 3 + 0] = Cin[idx];
            a[(ky * 3 + kx) * 3 + 1] = vx[idx];
            a[(ky * 3 + kx) * 3 + 2] = vy[idx];
        }
    }

    size_t obase = ((size_t)(pbase + y * HW + x)) * CH;
    for (int c4 = 0; c4 < 4; c4++) {
        float acc[16];
#pragma unroll
        for (int j = 0; j < 16; j++) acc[j] = b0[c4 * 16 + j];
#pragma unroll
        for (int k = 0; k < 27; k++) {
            float av = a[k];
            const float* wq = w0 + k * CH + c4 * 16;
#pragma unroll
            for (int j = 0; j < 16; j++) acc[j] = fmaf(av, wq[j], acc[j]);
        }
        unsigned short o[16];
#pragma unroll
        for (int j = 0; j < 16; j++) o[j] = f2bf(fmaxf(acc[j], 0.f));
        *reinterpret_cast<uint4*>(out + obase + c4 * 16)     = *reinterpret_cast<uint4*>(o);
        *reinterpret_cast<uint4*>(out + obase + c4 * 16 + 8) = *reinterpret_cast<uint4*>(o + 8);
    }
}

// ------------- Mid layers: double-buffered 4-tile pipeline -------------------
__global__ __launch_bounds__(512, 2) void k_mid_v10(
    const unsigned short* __restrict__ in,
    const unsigned short* __restrict__ wp,   // packed B-frags for this layer
    const float* __restrict__ b, unsigned short* __restrict__ out)
{
    __shared__ unsigned short sA[2][18 * 34 * CH];  // 2 x 78336 B = 156672 B

    const int t    = threadIdx.x;
    const int lane = t & 63;
    const int wid  = t >> 6;
    const int l15  = lane & 15;
    const int l4   = lane >> 4;

    const int tb = blockIdx.x * 4;   // 4 consecutive tiles per block

    // ---- prologue: stage tile 0 into sA[0] (R5-style runtime loop) ----
    {
        const int bz = tb >> 7, rr = tb & 127;
        const int y0 = (rr >> 3) * 16, x0 = (rr & 7) * 32;
        const size_t pbase = (size_t)bz * HW * HW;
        for (int g = t; g < 4896; g += 512) {
            int hp = g >> 3, cg = g & 7;
            int hr = hp / 34, hc = hp - hr * 34;
            int gy = (y0 + hr - 1) & MASK;
            int gx = (x0 + hc - 1) & MASK;
            uint4 v = *reinterpret_cast<const uint4*>(
                in + ((pbase + (size_t)gy * HW + gx) * CH + cg * 8));
            *reinterpret_cast<uint4*>(&sA[0][hp * 64 + ((cg ^ (hp & 7)) << 3)]) = v;
        }
    }

    // B-frag prefetch for q=0
    bf16x8 bnx[4];
#pragma unroll
    for (int n = 0; n < 4; n++)
        bnx[n] = *reinterpret_cast<const bf16x8*>(wp + (size_t)(n * 512 + lane * 8));

    __syncthreads();

    int pxb[4];   // tile-independent halo offsets
#pragma unroll
    for (int m = 0; m < 4; m++)
        pxb[m] = (2 * wid + (m >> 1)) * 34 + (m & 1) * 16 + l15;

    for (int it = 0; it < 4; ++it) {
        const int tid = tb + it;
        const int bz = tid >> 7, rr = tid & 127;
        const int y0 = (rr >> 3) * 16, x0 = (rr & 7) * 32;
        const size_t pbase = (size_t)bz * HW * HW;
        const unsigned short* sbuf = &sA[it & 1][0];

        // ---- issue next tile's staging loads (unconditional defs) ----
        uint4 st[10];
        {
            const int ntid = (tid + 1) & 1023;   // clamped-wrap; writes guarded
            const int nbz = ntid >> 7, nrr = ntid & 127;
            const int ny0 = (nrr >> 3) * 16, nx0 = (nrr & 7) * 32;
            const size_t npb = (size_t)nbz * HW * HW;
#pragma unroll
            for (int i2 = 0; i2 < 10; ++i2) {
                int gg = i2 * 512 + t; if (gg >= 4896) gg -= 4896;
                int hp = gg >> 3, cg = gg & 7;
                int hr = hp / 34, hc = hp - hr * 34;
                int gy = (ny0 + hr - 1) & MASK;
                int gx = (nx0 + hc - 1) & MASK;
                st[i2] = *reinterpret_cast<const uint4*>(
                    in + ((npb + (size_t)gy * HW + gx) * CH + cg * 8));
            }
        }

        // ---- accumulators ----
        f32x4 acc[4][4];
#pragma unroll
        for (int m = 0; m < 4; m++)
#pragma unroll
            for (int n = 0; n < 4; n++) {
                float bv = b[n * 16 + l15];
                acc[m][n] = (f32x4){bv, bv, bv, bv};
            }

        // ---- tap loop (verified R5 body, sbuf) ----
#pragma unroll
        for (int tap = 0; tap < 9; tap++) {
            const int koff = (tap / 3) * 34 + (tap % 3);
#pragma unroll
            for (int s = 0; s < 2; s++) {
                const int q = tap * 2 + s;
                bf16x8 bc[4];
#pragma unroll
                for (int n = 0; n < 4; n++) bc[n] = bnx[n];
                if (q < 17) {
#pragma unroll
                    for (int n = 0; n < 4; n++)
                        bnx[n] = *reinterpret_cast<const bf16x8*>(
                            wp + (size_t)(((q + 1) * 4 + n) * 512 + lane * 8));
                }
                const int o = s * 4 + l4;
#pragma unroll
                for (int m = 0; m < 4; m++) {
                    int px  = pxb[m] + koff;
                    int off = (px << 6) + (((o ^ px) & 7) << 3);
                    bf16x8 af = *reinterpret_cast<const bf16x8*>(&sbuf[off]);
#pragma unroll
                    for (int n = 0; n < 4; n++)
                        acc[m][n] = __builtin_amdgcn_mfma_f32_16x16x32_bf16(
                            af, bc[n], acc[m][n], 0, 0, 0);
                }
            }
        }

        // ---- write next tile into the other buffer ----
        if (it < 3) {
            unsigned short* dbuf = &sA[(it + 1) & 1][0];
#pragma unroll
            for (int i2 = 0; i2 < 10; ++i2) {
                int gg = i2 * 512 + t; if (gg >= 4896) gg -= 4896;
                int hp = gg >> 3, cg = gg & 7;
                *reinterpret_cast<uint4*>(
                    &dbuf[hp * 64 + ((cg ^ (hp & 7)) << 3)]) = st[i2];
            }
        }
        __syncthreads();

        // ---- epilogue stores AFTER barrier: drain under next tile's compute --
#pragma unroll
        for (int m = 0; m < 4; m++) {
            int y = y0 + 2 * wid + (m >> 1);
            int x = x0 + (m & 1) * 16;
            unsigned short* pm =
                out + (pbase + (size_t)y * HW + x) * CH + (l4 << 8) + l15;
#pragma unroll
            for (int n = 0; n < 4; n++)
#pragma unroll
                for (int j = 0; j < 4; j++)
                    pm[j * 64 + n * 16] = f2bf(fmaxf(acc[m][n][j], 0.f));
        }

        // reload B-frag q0 for the next tile
        if (it < 3) {
#pragma unroll
            for (int n = 0; n < 4; n++)
                bnx[n] = *reinterpret_cast<const bf16x8*>(
                    wp + (size_t)(n * 512 + lane * 8));
        }
    }
}

// -------- Output layer MFMA: 64ch -> 16 coeffs + fused 4x4 stencil dot -------
__global__ __launch_bounds__(512, 2) void k_out_mfma(
    const unsigned short* __restrict__ in, const float* __restrict__ w,
    const float* __restrict__ b, const float* __restrict__ Cin,
    float* __restrict__ out)
{
    __shared__ unsigned short sAct[18 * 34 * CH];   // 78336 B
    __shared__ unsigned short sW[9 * 128 * 8];      // 18432 B
    __shared__ float sC[19 * 35];                   // 2660 B

    const int t    = threadIdx.x;
    const int lane = t & 63;
    const int wid  = t >> 6;
    const int l15  = lane & 15;
    const int l4   = lane >> 4;
    const int x0   = blockIdx.x * 32;
    const int y0   = blockIdx.y * 16;
    const size_t pbase = (size_t)blockIdx.z * HW * HW;

    for (int g = t; g < 18 * 34 * 8; g += 512) {
        int hp = g >> 3, cg = g & 7;
        int hr = hp / 34, hc = hp - hr * 34;
        int gy = (y0 + hr - 1) & MASK;
        int gx = (x0 + hc - 1) & MASK;
        uint4 v = *reinterpret_cast<const uint4*>(
            in + ((pbase + gy * HW + gx) * CH + cg * 8));
        *reinterpret_cast<uint4*>(&sAct[hp * 64 + ((cg ^ (hp & 7)) << 3)]) = v;
    }
    for (int g = t; g < 1152; g += 512) {
        int tap = g >> 7, s = (g >> 6) & 1, dl = g & 63;
        int ci0 = s * 32 + (dl >> 4) * 8;
        int co  = dl & 15;
        unsigned short o8[8];
#pragma unroll
        for (int j = 0; j < 8; j++)
            o8[j] = f2bf(w[(tap * 64 + ci0 + j) * 16 + co]);
        *reinterpret_cast<uint4*>(&sW[g * 8]) = *reinterpret_cast<uint4*>(o8);
    }
    for (int g = t; g < 19 * 35; g += 512) {
        int r = g / 35, c2 = g - r * 35;
        int gy = (y0 + r - 2) & MASK;
        int gx = (x0 + c2 - 2) & MASK;
        sC[g] = Cin[pbase + gy * HW + gx];
    }
    __syncthreads();

    f32x4 acc[4];
    {
        float bv = b[l15];
#pragma unroll
        for (int m = 0; m < 4; m++) acc[m] = (f32x4){bv, bv, bv, bv};
    }

    int pxb[4];
#pragma unroll
    for (int m = 0; m < 4; m++)
        pxb[m] = (2 * wid + (m >> 1)) * 34 + (m & 1) * 16 + l15;

    for (int tap = 0; tap < 9; tap++) {
        const int koff = (tap / 3) * 34 + (tap % 3);
#pragma unroll
        for (int s = 0; s < 2; s++) {
            bf16x8 bf = *reinterpret_cast<const bf16x8*>(
                &sW[((tap * 2 + s) << 9) + (lane << 3)]);
            const int o = s * 4 + l4;
#pragma unroll
            for (int m = 0; m < 4; m++) {
                int px  = pxb[m] + koff;
                int off = (px << 6) + (((o ^ px) & 7) << 3);
                bf16x8 af = *reinterpret_cast<const bf16x8*>(&sAct[off]);
                acc[m] = __builtin_amdgcn_mfma_f32_16x16x32_bf16(
                    af, bf, acc[m], 0, 0, 0);
            }
        }
    }

#pragma unroll
    for (int m = 0; m < 4; m++) {
        int py = 2 * wid + (m >> 1);
        int xb = (m & 1) * 16 + l4 * 4;
#pragma unroll
        for (int j = 0; j < 4; j++) {
            int xt = xb + j;
            float v = acc[m][j] * sC[(py + (l15 >> 2)) * 35 + xt + (l15 & 3)];
            v += __shfl_xor(v, 1);
            v += __shfl_xor(v, 2);
            v += __shfl_xor(v, 4);
            v += __shfl_xor(v, 8);
            if (l15 == 0)
                out[pbase + (y0 + py) * HW + x0 + xt] = v;
        }
    }
}

extern "C" void kernel_launch(void* const* d_in, const int* in_sizes, int n_in,
                              void* d_out, int out_size, void* d_ws, size_t ws_size,
                              hipStream_t stream)
{
    (void)in_sizes; (void)n_in; (void)out_size; (void)ws_size;
    const float* Cin  = (const float*)d_in[0];
    const float* vx   = (const float*)d_in[1];
    const float* vy   = (const float*)d_in[2];
    const float* w0   = (const float*)d_in[3];
    const float* b0   = (const float*)d_in[4];
    const float* w1   = (const float*)d_in[5];
    const float* b1   = (const float*)d_in[6];
    const float* w2   = (const float*)d_in[7];
    const float* b2   = (const float*)d_in[8];
    const float* w3   = (const float*)d_in[9];
    const float* b3   = (const float*)d_in[10];
    const float* w4   = (const float*)d_in[11];
    const float* b4   = (const float*)d_in[12];
    const float* wout = (const float*)d_in[13];
    const float* bout = (const float*)d_in[14];

    unsigned short* actA = (unsigned short*)d_ws;
    unsigned short* actB = actA + (size_t)8 * HW * HW * CH;

    unsigned short* wpk = (unsigned short*)d_out;   // parked; k_out rewrites

    dim3 block(512);
    dim3 grid0(HW / TX, HW / TY, 8);
    dim3 gridM(256);
    dim3 gridO(HW / 32, HW / 16, 8);

    k_pack    <<<36, block, 0, stream>>>(w1, w2, w3, w4, wpk);
    k_layer0  <<<grid0, block, 0, stream>>>(Cin, vx, vy, w0, b0, actA);
    k_mid_v10 <<<gridM, block, 0, stream>>>(actA, wpk + 0 * 36864, b1, actB);
    k_mid_v10 <<<gridM, block, 0, stream>>>(actB, wpk + 1 * 36864, b2, actA);
    k_mid_v10 <<<gridM, block, 0, stream>>>(actA, wpk + 2 * 36864, b3, actB);
    k_mid_v10 <<<gridM, block, 0, stream>>>(actB, wpk + 3 * 36864, b4, actA);
    k_out_mfma<<<gridO, block, 0, stream>>>(actA, wout, bout, Cin, (float*)d_out);
}

// Round 12
// 285.073 us; speedup vs baseline: 3.4948x; 3.4948x over previous
//
#include <hip/hip_runtime.h>
#include <hip/hip_bf16.h>

// StencilNet round 11: R5 structure (verified 44.4us/mid) with MFMA operands
// swapped: A = packed weights (same buffer, A/B lane maps are symmetric),
// B = activations (same LDS read code). C/D now has 4 contiguous co per
// f32x4 -> epilogue is 16x 8B vector stores instead of 64x 2B scalar stores.
// Zero new register state (R8/R9/R10 spill lesson).

#define HW   256
#define MASK 255
#define CH   64
#define TX   32
#define TY   16

typedef short bf16x8 __attribute__((ext_vector_type(8)));
typedef float f32x4  __attribute__((ext_vector_type(4)));

__device__ __forceinline__ float bf2f(unsigned short u) {
    return __uint_as_float(((unsigned int)u) << 16);
}
__device__ __forceinline__ unsigned short f2bf(float f) {
    unsigned int x = __float_as_uint(f);
    return (unsigned short)((x + 0x7fffu + ((x >> 16) & 1u)) >> 16);  // RNE
}

// ---- pack mid-layer weights (identical to R5; doubles as A-frag layout) ----
__global__ __launch_bounds__(512) void k_pack(
    const float* __restrict__ w1, const float* __restrict__ w2,
    const float* __restrict__ w3, const float* __restrict__ w4,
    unsigned short* __restrict__ dst)
{
    int g = blockIdx.x * 512 + threadIdx.x;
    if (g >= 4 * 4608) return;
    int L = g / 4608, r = g - L * 4608;
    const float* w = (L == 0) ? w1 : (L == 1) ? w2 : (L == 2) ? w3 : w4;
    int q = r >> 8, n = (r >> 6) & 3, l = r & 63;
    int tap = q >> 1, s = q & 1;
    int ci0 = s * 32 + ((l >> 4) << 3);
    int co  = n * 16 + (l & 15);
    unsigned short o8[8];
#pragma unroll
    for (int j = 0; j < 8; j++)
        o8[j] = f2bf(w[(tap * 64 + ci0 + j) * 64 + co]);
    *reinterpret_cast<uint4*>(dst + (size_t)g * 8) = *reinterpret_cast<uint4*>(o8);
}

// ---------------- Layer 0: [C,vx,vy] (3ch f32) -> 64ch bf16, ReLU -------------
__global__ __launch_bounds__(512) void k_layer0(
    const float* __restrict__ Cin, const float* __restrict__ vx,
    const float* __restrict__ vy, const float* __restrict__ w0,
    const float* __restrict__ b0, unsigned short* __restrict__ out)
{
    int t  = threadIdx.x;
    int lx = t & 31, ly = t >> 5;
    int x  = blockIdx.x * TX + lx;
    int y  = blockIdx.y * TY + ly;
    int bb = blockIdx.z;
    int pbase = bb * HW * HW;

    float a[27];
#pragma unroll
    for (int ky = 0; ky < 3; ky++) {
        int yy = (y + ky - 1) & MASK;
#pragma unroll
        for (int kx = 0; kx < 3; kx++) {
            int xx  = (x + kx - 1) & MASK;
            int idx = pbase + yy * HW + xx;
            a[(ky * 3 + kx) * 3 + 0] = Cin[idx];
            a[(ky * 3 + kx) * 3 + 1] = vx[idx];
            a[(ky * 3 + kx) * 3 + 2] = vy[idx];
        }
    }

    size_t obase = ((size_t)(pbase + y * HW + x)) * CH;
    for (int c4 = 0; c4 < 4; c4++) {
        float acc[16];
#pragma unroll
        for (int j = 0; j < 16; j++) acc[j] = b0[c4 * 16 + j];
#pragma unroll
        for (int k = 0; k < 27; k++) {
            float av = a[k];
            const float* wq = w0 + k * CH + c4 * 16;
#pragma unroll
            for (int j = 0; j < 16; j++) acc[j] = fmaf(av, wq[j], acc[j]);
        }
        unsigned short o[16];
#pragma unroll
        for (int j = 0; j < 16; j++) o[j] = f2bf(fmaxf(acc[j], 0.f));
        *reinterpret_cast<uint4*>(out + obase + c4 * 16)     = *reinterpret_cast<uint4*>(o);
        *reinterpret_cast<uint4*>(out + obase + c4 * 16 + 8) = *reinterpret_cast<uint4*>(o + 8);
    }
}

// ------------- Mid layers: swapped-operand MFMA, vectorized epilogue ---------
__global__ __launch_bounds__(512, 4) void k_mid_v11(
    const unsigned short* __restrict__ in,
    const unsigned short* __restrict__ wp,   // packed frags for this layer
    const float* __restrict__ b, unsigned short* __restrict__ out)
{
    __shared__ unsigned short sAct[18 * 34 * CH];  // 78336 B -> 2 blocks/CU

    const int t    = threadIdx.x;
    const int lane = t & 63;
    const int wid  = t >> 6;
    const int l15  = lane & 15;
    const int l4   = lane >> 4;

    // bijective XCD-chunked swizzle: 1024 blocks = 8 chunks of 128
    const int bid = blockIdx.x;
    const int tid = (bid & 7) * 128 + (bid >> 3);
    const int bz  = tid >> 7;
    const int rr  = tid & 127;
    const int y0  = (rr >> 3) * 16;
    const int x0  = (rr & 7) * 32;
    const size_t pbase = (size_t)bz * HW * HW;

    // ---- stage act halo 18x34x64 (bf16), XOR-swizzled (R5 verbatim) ----
    for (int g = t; g < 18 * 34 * 8; g += 512) {
        int hp = g >> 3, cg = g & 7;
        int hr = hp / 34, hc = hp - hr * 34;
        int gy = (y0 + hr - 1) & MASK;
        int gx = (x0 + hc - 1) & MASK;
        uint4 v = *reinterpret_cast<const uint4*>(
            in + ((pbase + (size_t)gy * HW + gx) * CH + cg * 8));
        *reinterpret_cast<uint4*>(&sAct[hp * 64 + ((cg ^ (hp & 7)) << 3)]) = v;
    }

    // weight A-frag prefetch for q=0
    bf16x8 bnx[4];
#pragma unroll
    for (int m = 0; m < 4; m++)
        bnx[m] = *reinterpret_cast<const bf16x8*>(wp + (size_t)(m * 512 + lane * 8));

    __syncthreads();   // the only barrier

    // acc[m][n]: co = m*16 + l4*4 + j  (4 contiguous co per f32x4), px per n
    f32x4 acc[4][4];
#pragma unroll
    for (int m = 0; m < 4; m++) {
        const float4 bv = *reinterpret_cast<const float4*>(b + m * 16 + l4 * 4);
#pragma unroll
        for (int n = 0; n < 4; n++)
            acc[m][n] = (f32x4){bv.x, bv.y, bv.z, bv.w};
    }

    int pxb[4];
#pragma unroll
    for (int n = 0; n < 4; n++)
        pxb[n] = (2 * wid + (n >> 1)) * 34 + (n & 1) * 16 + l15;

#pragma unroll
    for (int tap = 0; tap < 9; tap++) {
        const int koff = (tap / 3) * 34 + (tap % 3);
#pragma unroll
        for (int s = 0; s < 2; s++) {
            const int q = tap * 2 + s;
            bf16x8 wa[4];
#pragma unroll
            for (int m = 0; m < 4; m++) wa[m] = bnx[m];
            if (q < 17) {
#pragma unroll
                for (int m = 0; m < 4; m++)
                    bnx[m] = *reinterpret_cast<const bf16x8*>(
                        wp + (size_t)(((q + 1) * 4 + m) * 512 + lane * 8));
            }
            const int o = s * 4 + l4;
#pragma unroll
            for (int n = 0; n < 4; n++) {
                int px  = pxb[n] + koff;
                int off = (px << 6) + (((o ^ px) & 7) << 3);
                bf16x8 af = *reinterpret_cast<const bf16x8*>(&sAct[off]);
#pragma unroll
                for (int m = 0; m < 4; m++)
                    acc[m][n] = __builtin_amdgcn_mfma_f32_16x16x32_bf16(
                        wa[m], af, acc[m][n], 0, 0, 0);
            }
        }
    }

    // ---- epilogue: ReLU -> bf16, 16x 8B vector stores ----
    // D: col = l15 = px within n-frag, row = l4*4+j = co within m-frag
#pragma unroll
    for (int n = 0; n < 4; n++) {
        int y = y0 + 2 * wid + (n >> 1);
        int x = x0 + (n & 1) * 16 + l15;
        unsigned short* pm = out + (pbase + (size_t)y * HW + x) * CH + l4 * 4;
#pragma unroll
        for (int m = 0; m < 4; m++) {
            unsigned short o4[4];
#pragma unroll
            for (int j = 0; j < 4; j++)
                o4[j] = f2bf(fmaxf(acc[m][n][j], 0.f));
            *reinterpret_cast<uint2*>(pm + m * 16) = *reinterpret_cast<uint2*>(o4);
        }
    }
}

// -------- Output layer MFMA: 64ch -> 16 coeffs + fused 4x4 stencil dot -------
__global__ __launch_bounds__(512, 2) void k_out_mfma(
    const unsigned short* __restrict__ in, const float* __restrict__ w,
    const float* __restrict__ b, const float* __restrict__ Cin,
    float* __restrict__ out)
{
    __shared__ unsigned short sAct[18 * 34 * CH];   // 78336 B
    __shared__ unsigned short sW[9 * 128 * 8];      // 18432 B
    __shared__ float sC[19 * 35];                   // 2660 B

    const int t    = threadIdx.x;
    const int lane = t & 63;
    const int wid  = t >> 6;
    const int l15  = lane & 15;
    const int l4   = lane >> 4;
    const int x0   = blockIdx.x * 32;
    const int y0   = blockIdx.y * 16;
    const size_t pbase = (size_t)blockIdx.z * HW * HW;

    for (int g = t; g < 18 * 34 * 8; g += 512) {
        int hp = g >> 3, cg = g & 7;
        int hr = hp / 34, hc = hp - hr * 34;
        int gy = (y0 + hr - 1) & MASK;
        int gx = (x0 + hc - 1) & MASK;
        uint4 v = *reinterpret_cast<const uint4*>(
            in + ((pbase + gy * HW + gx) * CH + cg * 8));
        *reinterpret_cast<uint4*>(&sAct[hp * 64 + ((cg ^ (hp & 7)) << 3)]) = v;
    }
    for (int g = t; g < 1152; g += 512) {
        int tap = g >> 7, s = (g >> 6) & 1, dl = g & 63;
        int ci0 = s * 32 + (dl >> 4) * 8;
        int co  = dl & 15;
        unsigned short o8[8];
#pragma unroll
        for (int j = 0; j < 8; j++)
            o8[j] = f2bf(w[(tap * 64 + ci0 + j) * 16 + co]);
        *reinterpret_cast<uint4*>(&sW[g * 8]) = *reinterpret_cast<uint4*>(o8);
    }
    for (int g = t; g < 19 * 35; g += 512) {
        int r = g / 35, c2 = g - r * 35;
        int gy = (y0 + r - 2) & MASK;
        int gx = (x0 + c2 - 2) & MASK;
        sC[g] = Cin[pbase + gy * HW + gx];
    }
    __syncthreads();

    f32x4 acc[4];
    {
        float bv = b[l15];
#pragma unroll
        for (int m = 0; m < 4; m++) acc[m] = (f32x4){bv, bv, bv, bv};
    }

    int pxb[4];
#pragma unroll
    for (int m = 0; m < 4; m++)
        pxb[m] = (2 * wid + (m >> 1)) * 34 + (m & 1) * 16 + l15;

    for (int tap = 0; tap < 9; tap++) {
        const int koff = (tap / 3) * 34 + (tap % 3);
#pragma unroll
        for (int s = 0; s < 2; s++) {
            bf16x8 bf = *reinterpret_cast<const bf16x8*>(
                &sW[((tap * 2 + s) << 9) + (lane << 3)]);
            const int o = s * 4 + l4;
#pragma unroll
            for (int m = 0; m < 4; m++) {
                int px  = pxb[m] + koff;
                int off = (px << 6) + (((o ^ px) & 7) << 3);
                bf16x8 af = *reinterpret_cast<const bf16x8*>(&sAct[off]);
                acc[m] = __builtin_amdgcn_mfma_f32_16x16x32_bf16(
                    af, bf, acc[m], 0, 0, 0);
            }
        }
    }

#pragma unroll
    for (int m = 0; m < 4; m++) {
        int py = 2 * wid + (m >> 1);
        int xb = (m & 1) * 16 + l4 * 4;
#pragma unroll
        for (int j = 0; j < 4; j++) {
            int xt = xb + j;
            float v = acc[m][j] * sC[(py + (l15 >> 2)) * 35 + xt + (l15 & 3)];
            v += __shfl_xor(v, 1);
            v += __shfl_xor(v, 2);
            v += __shfl_xor(v, 4);
            v += __shfl_xor(v, 8);
            if (l15 == 0)
                out[pbase + (y0 + py) * HW + x0 + xt] = v;
        }
    }
}

extern "C" void kernel_launch(void* const* d_in, const int* in_sizes, int n_in,
                              void* d_out, int out_size, void* d_ws, size_t ws_size,
                              hipStream_t stream)
{
    (void)in_sizes; (void)n_in; (void)out_size; (void)ws_size;
    const float* Cin  = (const float*)d_in[0];
    const float* vx   = (const float*)d_in[1];
    const float* vy   = (const float*)d_in[2];
    const float* w0   = (const float*)d_in[3];
    const float* b0   = (const float*)d_in[4];
    const float* w1   = (const float*)d_in[5];
    const float* b1   = (const float*)d_in[6];
    const float* w2   = (const float*)d_in[7];
    const float* b2   = (const float*)d_in[8];
    const float* w3   = (const float*)d_in[9];
    const float* b3   = (const float*)d_in[10];
    const float* w4   = (const float*)d_in[11];
    const float* b4   = (const float*)d_in[12];
    const float* wout = (const float*)d_in[13];
    const float* bout = (const float*)d_in[14];

    unsigned short* actA = (unsigned short*)d_ws;
    unsigned short* actB = actA + (size_t)8 * HW * HW * CH;

    unsigned short* wpk = (unsigned short*)d_out;   // parked; k_out rewrites

    dim3 block(512);
    dim3 grid0(HW / TX, HW / TY, 8);
    dim3 gridM(1024);
    dim3 gridO(HW / 32, HW / 16, 8);

    k_pack    <<<36, block, 0, stream>>>(w1, w2, w3, w4, wpk);
    k_layer0  <<<grid0, block, 0, stream>>>(Cin, vx, vy, w0, b0, actA);
    k_mid_v11 <<<gridM, block, 0, stream>>>(actA, wpk + 0 * 36864, b1, actB);
    k_mid_v11 <<<gridM, block, 0, stream>>>(actB, wpk + 1 * 36864, b2, actA);
    k_mid_v11 <<<gridM, block, 0, stream>>>(actA, wpk + 2 * 36864, b3, actB);
    k_mid_v11 <<<gridM, block, 0, stream>>>(actB, wpk + 3 * 36864, b4, actA);
    k_out_mfma<<<gridO, block, 0, stream>>>(actA, wout, bout, Cin, (float*)d_out);
}